// Round 2
// baseline (2546.322 us; speedup 1.0000x reference)
//
#include <hip/hip_runtime.h>

#define N_NODES 100000
#define N_EDGES 6400000
#define IN_CH   128
#define HID     32

#define BKT_SHIFT 6
#define BKT_MASK  63
#define BKT_SZ    64
#define NBKT      1563          // ceil(100000/64)
#define NBLK      256           // histogram/scatter tiles
#define TILE      25000         // 6.4M / 256 exactly

// ---------- ws layout (bytes) ----------
#define O_EBUF 0u               // 6.4M * 4B = 25,600,000
#define O_HS   25600000u        // 12,800,000
#define O_HS2  38400000u        // 12,800,000 (overlaid below until agg1 writes it)
#define O_GH   38400000u        //   ghist:   256*1563*4 = 1,600,512
#define O_CUR  40000512u        //   cursors: 1,600,512 (ends 41,601,024 < 51,200,000)
#define O_BST  51200000u        // (NBKT+1)*4 = 6,256  (pad to 8192)
#define O_BTOT 51208192u        // NBKT*4 (pad to 8192)
#define O_DINV 51216384u        // 400,000
#define O_FLAG 51616384u        // 4
// total ~51.62 MB (<= previous 52.8 MB footprint that fit)

// Detect whether edge_index buffer is int64 (high words all zero) or int32.
__global__ void k_detect(const unsigned int* e, int* flag) {
    __shared__ int any;
    if (threadIdx.x == 0) any = 0;
    __syncthreads();
    int acc = 0;
    for (int i = threadIdx.x; i < 4096; i += 256)
        acc |= (e[2 * i + 1] != 0u);
    if (acc) atomicOr(&any, 1);
    __syncthreads();
    if (threadIdx.x == 0) *flag = any ? 0 : 1;   // 1 => int64
}

__device__ __forceinline__ int eload(const int* e, int is64, long long idx) {
    return is64 ? e[2 * (size_t)idx] : e[(size_t)idx];
}

// Per-tile histogram over destination buckets (LDS atomics only).
__global__ void k_hist(const int* e, const int* flag, int* ghist) {
    __shared__ int h[NBKT];
    for (int i = threadIdx.x; i < NBKT; i += 256) h[i] = 0;
    __syncthreads();
    int is64 = *flag;
    long long base = (long long)blockIdx.x * TILE;
    for (int k = threadIdx.x; k < TILE; k += 256) {
        int dst = eload(e, is64, (long long)N_EDGES + base + k);
        atomicAdd(&h[dst >> BKT_SHIFT], 1);
    }
    __syncthreads();
    int* g = ghist + blockIdx.x * NBKT;
    for (int i = threadIdx.x; i < NBKT; i += 256) g[i] = h[i];
}

// btot[j] = sum over tiles of ghist[blk][j]
__global__ void k_scan1(const int* __restrict__ ghist, int* __restrict__ btot) {
    int j = blockIdx.x * 256 + threadIdx.x;
    if (j >= NBKT) return;
    int t = 0;
    for (int blk = 0; blk < NBLK; ++blk) t += ghist[blk * NBKT + j];
    btot[j] = t;
}

// exclusive scan of btot -> bstart (single block, two bins per thread)
__global__ void k_scan2(const int* __restrict__ btot, int* __restrict__ bstart) {
    __shared__ int s[1024];
    int t = threadIdx.x;
    int j0 = t * 2, j1 = t * 2 + 1;
    int a = (j0 < NBKT) ? btot[j0] : 0;
    int b = (j1 < NBKT) ? btot[j1] : 0;
    s[t] = a + b;
    __syncthreads();
    for (int off = 1; off < 1024; off <<= 1) {
        int v = (t >= off) ? s[t - off] : 0;
        __syncthreads();
        s[t] += v;
        __syncthreads();
    }
    int excl = s[t] - (a + b);
    if (j0 < NBKT) bstart[j0] = excl;
    if (j1 < NBKT) bstart[j1] = excl + a;
    if (t == 0) bstart[NBKT] = N_EDGES;
}

// cursors[blk][j] = bstart[j] + prefix over earlier tiles
__global__ void k_scan3(const int* __restrict__ ghist, const int* __restrict__ bstart,
                        int* __restrict__ cursors) {
    int j = blockIdx.x * 256 + threadIdx.x;
    if (j >= NBKT) return;
    int run = bstart[j];
    for (int blk = 0; blk < NBLK; ++blk) {
        cursors[blk * NBKT + j] = run;
        run += ghist[blk * NBKT + j];
    }
}

// Scatter edges into bucket-grouped ebuf; packed (src<<6)|(dst&63). LDS cursors.
__global__ void k_scatter(const int* e, const int* flag, const int* __restrict__ cursors,
                          unsigned int* __restrict__ ebuf) {
    __shared__ int cur[NBKT];
    const int* c = cursors + blockIdx.x * NBKT;
    for (int i = threadIdx.x; i < NBKT; i += 256) cur[i] = c[i];
    __syncthreads();
    int is64 = *flag;
    long long base = (long long)blockIdx.x * TILE;
    for (int k = threadIdx.x; k < TILE; k += 256) {
        int src = eload(e, is64, base + k);
        int dst = eload(e, is64, (long long)N_EDGES + base + k);
        int pos = atomicAdd(&cur[dst >> BKT_SHIFT], 1);
        ebuf[pos] = ((unsigned)src << BKT_SHIFT) | (unsigned)(dst & BKT_MASK);
    }
}

// Per-bucket degree -> dinv (LDS counters only)
__global__ void k_deg(const unsigned int* __restrict__ ebuf, const int* __restrict__ bstart,
                      float* __restrict__ dinv) {
    __shared__ int deg[BKT_SZ];
    if (threadIdx.x < BKT_SZ) deg[threadIdx.x] = 0;
    __syncthreads();
    int b = blockIdx.x;
    int s0 = bstart[b], e0 = bstart[b + 1];
    for (int i = s0 + threadIdx.x; i < e0; i += 256)
        atomicAdd(&deg[ebuf[i] & BKT_MASK], 1);
    __syncthreads();
    if (threadIdx.x < BKT_SZ) {
        int node = b * BKT_SZ + threadIdx.x;
        if (node < N_NODES) dinv[node] = rsqrtf((float)(deg[threadIdx.x] + 1));
    }
}

// hs[i][c] = dinv[i] * sum_k x[i][k] * W1[k][c]
__launch_bounds__(256)
__global__ void k_gemm1(const float* __restrict__ x, const float* __restrict__ W1,
                        const float* __restrict__ dinv, float* __restrict__ hs) {
    __shared__ float w[IN_CH * HID];
    for (int i = threadIdx.x; i < IN_CH * HID; i += 256) w[i] = W1[i];
    __syncthreads();
    int lane = threadIdx.x & 31;
    int node = blockIdx.x * 8 + (threadIdx.x >> 5);
    const float4* xr = (const float4*)(x + (size_t)node * IN_CH);
    float acc = 0.f;
#pragma unroll
    for (int k4 = 0; k4 < IN_CH / 4; ++k4) {
        float4 xv = xr[k4];
        acc += xv.x * w[(k4 * 4 + 0) * HID + lane];
        acc += xv.y * w[(k4 * 4 + 1) * HID + lane];
        acc += xv.z * w[(k4 * 4 + 2) * HID + lane];
        acc += xv.w * w[(k4 * 4 + 3) * HID + lane];
    }
    hs[(size_t)node * HID + lane] = acc * dinv[node];
}

// conv1 aggregation (LDS accumulators, LDS float atomics) + relu + fused W2 GEMM:
// hs2[i][c] = dinv[i] * sum_k relu(conv1)[i][k] * W2[k][c]
__launch_bounds__(256)
__global__ void k_agg1(const float* __restrict__ hs, const unsigned int* __restrict__ ebuf,
                       const int* __restrict__ bstart, const float* __restrict__ dinv,
                       const float* __restrict__ b1, const float* __restrict__ W2,
                       float* __restrict__ hs2) {
    __shared__ float acc[BKT_SZ * HID];     // 8 KB
    __shared__ float w2[HID * HID];         // 4 KB
    int blk = blockIdx.x;
    int nbase = blk * BKT_SZ;
    for (int i = threadIdx.x; i < HID * HID; i += 256) w2[i] = W2[i];
    for (int idx = threadIdx.x; idx < BKT_SZ * HID; idx += 256) {
        int node = nbase + (idx >> 5);
        acc[idx] = (node < N_NODES) ? hs[(size_t)node * HID + (idx & 31)] : 0.f;  // self loop
    }
    __syncthreads();
    int lane = threadIdx.x & 31, hw = threadIdx.x >> 5;
    int s0 = bstart[blk], e0 = bstart[blk + 1];
    for (int i0 = s0 + hw * 4; i0 < e0; i0 += 32) {       // 4-deep ILP per half-wave
        int nrem = e0 - i0;
        unsigned v0 = ebuf[i0];
        unsigned v1 = (nrem > 1) ? ebuf[i0 + 1] : v0;
        unsigned v2 = (nrem > 2) ? ebuf[i0 + 2] : v0;
        unsigned v3 = (nrem > 3) ? ebuf[i0 + 3] : v0;
        float f0 = hs[(size_t)(v0 >> BKT_SHIFT) * HID + lane];
        float f1 = hs[(size_t)(v1 >> BKT_SHIFT) * HID + lane];
        float f2 = hs[(size_t)(v2 >> BKT_SHIFT) * HID + lane];
        float f3 = hs[(size_t)(v3 >> BKT_SHIFT) * HID + lane];
        atomicAdd(&acc[(v0 & BKT_MASK) * HID + lane], f0);
        if (nrem > 1) atomicAdd(&acc[(v1 & BKT_MASK) * HID + lane], f1);
        if (nrem > 2) atomicAdd(&acc[(v2 & BKT_MASK) * HID + lane], f2);
        if (nrem > 3) atomicAdd(&acc[(v3 & BKT_MASK) * HID + lane], f3);
    }
    __syncthreads();
    // finalize conv1: h1 = relu(acc*dinv + b1), in place
    for (int idx = threadIdx.x; idx < BKT_SZ * HID; idx += 256) {
        int node = nbase + (idx >> 5);
        float dv = (node < N_NODES) ? dinv[node] : 0.f;
        acc[idx] = fmaxf(acc[idx] * dv + b1[idx & 31], 0.f);
    }
    __syncthreads();
    // fused GEMM: hs2 = (h1 @ W2) * dinv
    for (int n = hw; n < BKT_SZ; n += 8) {
        int node = nbase + n;
        if (node >= N_NODES) continue;
        float a = 0.f;
#pragma unroll
        for (int k = 0; k < HID; ++k) a += acc[n * HID + k] * w2[k * HID + lane];
        hs2[(size_t)node * HID + lane] = a * dinv[node];
    }
}

// conv2 aggregation + relu + fused MLP head
__launch_bounds__(256)
__global__ void k_agg2(const float* __restrict__ hs2, const unsigned int* __restrict__ ebuf,
                       const int* __restrict__ bstart, const float* __restrict__ dinv,
                       const float* __restrict__ b2,
                       const float* __restrict__ Wl1, const float* __restrict__ bl1,
                       const float* __restrict__ Wl2, const float* __restrict__ bl2,
                       float* __restrict__ out) {
    __shared__ float acc[BKT_SZ * HID];     // 8 KB
    __shared__ float wl1[HID * HID];        // 4 KB
    int blk = blockIdx.x;
    int nbase = blk * BKT_SZ;
    for (int i = threadIdx.x; i < HID * HID; i += 256) wl1[i] = Wl1[i];
    for (int idx = threadIdx.x; idx < BKT_SZ * HID; idx += 256) {
        int node = nbase + (idx >> 5);
        acc[idx] = (node < N_NODES) ? hs2[(size_t)node * HID + (idx & 31)] : 0.f;
    }
    __syncthreads();
    int lane = threadIdx.x & 31, hw = threadIdx.x >> 5;
    int s0 = bstart[blk], e0 = bstart[blk + 1];
    for (int i0 = s0 + hw * 4; i0 < e0; i0 += 32) {
        int nrem = e0 - i0;
        unsigned v0 = ebuf[i0];
        unsigned v1 = (nrem > 1) ? ebuf[i0 + 1] : v0;
        unsigned v2 = (nrem > 2) ? ebuf[i0 + 2] : v0;
        unsigned v3 = (nrem > 3) ? ebuf[i0 + 3] : v0;
        float f0 = hs2[(size_t)(v0 >> BKT_SHIFT) * HID + lane];
        float f1 = hs2[(size_t)(v1 >> BKT_SHIFT) * HID + lane];
        float f2 = hs2[(size_t)(v2 >> BKT_SHIFT) * HID + lane];
        float f3 = hs2[(size_t)(v3 >> BKT_SHIFT) * HID + lane];
        atomicAdd(&acc[(v0 & BKT_MASK) * HID + lane], f0);
        if (nrem > 1) atomicAdd(&acc[(v1 & BKT_MASK) * HID + lane], f1);
        if (nrem > 2) atomicAdd(&acc[(v2 & BKT_MASK) * HID + lane], f2);
        if (nrem > 3) atomicAdd(&acc[(v3 & BKT_MASK) * HID + lane], f3);
    }
    __syncthreads();
    // h2 = relu(acc*dinv + b2), in place
    for (int idx = threadIdx.x; idx < BKT_SZ * HID; idx += 256) {
        int node = nbase + (idx >> 5);
        float dv = (node < N_NODES) ? dinv[node] : 0.f;
        acc[idx] = fmaxf(acc[idx] * dv + b2[idx & 31], 0.f);
    }
    __syncthreads();
    // head: out = relu(h2 @ Wl1 + bl1) @ Wl2 + bl2
    float w2v = Wl2[lane], bb = *bl2;
    for (int n = hw; n < BKT_SZ; n += 8) {
        int node = nbase + n;
        if (node >= N_NODES) continue;
        float a = bl1[lane];
#pragma unroll
        for (int k = 0; k < HID; ++k) a += acc[n * HID + k] * wl1[k * HID + lane];
        float o = fmaxf(a, 0.f) * w2v;
#pragma unroll
        for (int off = 16; off; off >>= 1) o += __shfl_down(o, off, 32);
        if (lane == 0) out[node] = o + bb;
    }
}

extern "C" void kernel_launch(void* const* d_in, const int* in_sizes, int n_in,
                              void* d_out, int out_size, void* d_ws, size_t ws_size,
                              hipStream_t stream) {
    const float* x   = (const float*)d_in[0];
    const int*   e   = (const int*)d_in[1];
    const float* W1  = (const float*)d_in[2];
    const float* b1  = (const float*)d_in[3];
    const float* W2  = (const float*)d_in[4];
    const float* b2  = (const float*)d_in[5];
    const float* Wl1 = (const float*)d_in[6];
    const float* bl1 = (const float*)d_in[7];
    const float* Wl2 = (const float*)d_in[8];
    const float* bl2 = (const float*)d_in[9];
    float* out = (float*)d_out;

    char* w = (char*)d_ws;
    unsigned int* ebuf   = (unsigned int*)(w + O_EBUF);
    float*        hs     = (float*)(w + O_HS);
    float*        hs2    = (float*)(w + O_HS2);
    int*          ghist  = (int*)(w + O_GH);
    int*          cursors= (int*)(w + O_CUR);
    int*          bstart = (int*)(w + O_BST);
    int*          btot   = (int*)(w + O_BTOT);
    float*        dinv   = (float*)(w + O_DINV);
    int*          flag   = (int*)(w + O_FLAG);

    const int NB_BIN  = (NBKT + 255) / 256;   // 7
    const int NB_NODE = N_NODES / 8;          // 12500 (exact)

    k_detect<<<1, 256, 0, stream>>>((const unsigned int*)e, flag);
    k_hist<<<NBLK, 256, 0, stream>>>(e, flag, ghist);
    k_scan1<<<NB_BIN, 256, 0, stream>>>(ghist, btot);
    k_scan2<<<1, 1024, 0, stream>>>(btot, bstart);
    k_scan3<<<NB_BIN, 256, 0, stream>>>(ghist, bstart, cursors);
    k_scatter<<<NBLK, 256, 0, stream>>>(e, flag, cursors, ebuf);
    k_deg<<<NBKT, 256, 0, stream>>>(ebuf, bstart, dinv);

    k_gemm1<<<NB_NODE, 256, 0, stream>>>(x, W1, dinv, hs);
    k_agg1<<<NBKT, 256, 0, stream>>>(hs, ebuf, bstart, dinv, b1, W2, hs2);
    k_agg2<<<NBKT, 256, 0, stream>>>(hs2, ebuf, bstart, dinv, b2,
                                     Wl1, bl1, Wl2, bl2, out);
}

// Round 3
// 420.837 us; speedup vs baseline: 6.0506x; 6.0506x over previous
//
#include <hip/hip_runtime.h>

#define N_NODES 100000
#define N_EDGES 6400000
#define IN_CH   128
#define HID     32

#define BKT_SHIFT 6
#define BKT_MASK  63
#define BKT_SZ    64
#define NBKT      1563          // ceil(100000/64)
#define NBLK      256           // histogram/scatter tiles
#define TILE      25000         // 6.4M / 256 exactly

// ---------- ws layout (bytes) ----------
// region A [0, 25.6M): ebuf during build; then hs | hs2 after k_sort2
#define O_EBUF 0u
#define O_HS   0u
#define O_HS2  12800000u
// region B [25.6M, 51.2M): ghist+cursors during build; then csr (k_sort2 output)
#define O_GH   25600000u        // 256*1563*4 = 1,600,512
#define O_CUR  27200512u        // 1,600,512
#define O_CSR  25600000u        // 25,600,000 (clobbers ghist/cursors - dead by then)
// small persistent region
#define O_ROWS 51200000u        // (N_NODES+1)*4 = 400,004
#define O_DINV 51700000u        // 400,000
#define O_BST  52200000u        // (NBKT+1)*4
#define O_BTOT 52300000u        // NBKT*4
#define O_FLAG 52400000u        // 4
// total ~52.4 MB (<= 52.8 MB proven in R1)

// Detect whether edge_index buffer is int64 (high words all zero) or int32.
__global__ void k_detect(const unsigned int* e, int* flag) {
    __shared__ int any;
    if (threadIdx.x == 0) any = 0;
    __syncthreads();
    int acc = 0;
    for (int i = threadIdx.x; i < 4096; i += 256)
        acc |= (e[2 * i + 1] != 0u);
    if (acc) atomicOr(&any, 1);
    __syncthreads();
    if (threadIdx.x == 0) *flag = any ? 0 : 1;   // 1 => int64
}

__device__ __forceinline__ int eload(const int* e, int is64, long long idx) {
    return is64 ? e[2 * (size_t)idx] : e[(size_t)idx];
}

// Per-tile histogram over destination buckets (LDS int atomics only).
__global__ void k_hist(const int* e, const int* flag, int* ghist) {
    __shared__ int h[NBKT];
    for (int i = threadIdx.x; i < NBKT; i += 256) h[i] = 0;
    __syncthreads();
    int is64 = *flag;
    long long base = (long long)blockIdx.x * TILE;
    for (int k = threadIdx.x; k < TILE; k += 256) {
        int dst = eload(e, is64, (long long)N_EDGES + base + k);
        atomicAdd(&h[dst >> BKT_SHIFT], 1);
    }
    __syncthreads();
    int* g = ghist + blockIdx.x * NBKT;
    for (int i = threadIdx.x; i < NBKT; i += 256) g[i] = h[i];
}

// btot[j] = sum over tiles of ghist[blk][j]
__global__ void k_scan1(const int* __restrict__ ghist, int* __restrict__ btot) {
    int j = blockIdx.x * 256 + threadIdx.x;
    if (j >= NBKT) return;
    int t = 0;
    for (int blk = 0; blk < NBLK; ++blk) t += ghist[blk * NBKT + j];
    btot[j] = t;
}

// exclusive scan of btot -> bstart (single block, two bins per thread)
__global__ void k_scan2(const int* __restrict__ btot, int* __restrict__ bstart) {
    __shared__ int s[1024];
    int t = threadIdx.x;
    int j0 = t * 2, j1 = t * 2 + 1;
    int a = (j0 < NBKT) ? btot[j0] : 0;
    int b = (j1 < NBKT) ? btot[j1] : 0;
    s[t] = a + b;
    __syncthreads();
    for (int off = 1; off < 1024; off <<= 1) {
        int v = (t >= off) ? s[t - off] : 0;
        __syncthreads();
        s[t] += v;
        __syncthreads();
    }
    int excl = s[t] - (a + b);
    if (j0 < NBKT) bstart[j0] = excl;
    if (j1 < NBKT) bstart[j1] = excl + a;
    if (t == 0) bstart[NBKT] = N_EDGES;
}

// cursors[blk][j] = bstart[j] + prefix over earlier tiles
__global__ void k_scan3(const int* __restrict__ ghist, const int* __restrict__ bstart,
                        int* __restrict__ cursors) {
    int j = blockIdx.x * 256 + threadIdx.x;
    if (j >= NBKT) return;
    int run = bstart[j];
    for (int blk = 0; blk < NBLK; ++blk) {
        cursors[blk * NBKT + j] = run;
        run += ghist[blk * NBKT + j];
    }
}

// Scatter edges into bucket-grouped ebuf; packed (src<<6)|(dst&63). LDS cursors.
__global__ void k_scatter(const int* e, const int* flag, const int* __restrict__ cursors,
                          unsigned int* __restrict__ ebuf) {
    __shared__ int cur[NBKT];
    const int* c = cursors + blockIdx.x * NBKT;
    for (int i = threadIdx.x; i < NBKT; i += 256) cur[i] = c[i];
    __syncthreads();
    int is64 = *flag;
    long long base = (long long)blockIdx.x * TILE;
    for (int k = threadIdx.x; k < TILE; k += 256) {
        int src = eload(e, is64, base + k);
        int dst = eload(e, is64, (long long)N_EDGES + base + k);
        int pos = atomicAdd(&cur[dst >> BKT_SHIFT], 1);
        ebuf[pos] = ((unsigned)src << BKT_SHIFT) | (unsigned)(dst & BKT_MASK);
    }
}

// Per-bucket counting sort: ebuf bucket segment -> node-sorted csr (src ids),
// plus per-node row starts and dinv. LDS int atomics only; writes land in a
// bucket-local ~16KB window (no k_fill-style 64B write amplification).
__global__ void k_sort2(const unsigned int* __restrict__ ebuf, const int* __restrict__ bstart,
                        int* __restrict__ csr, int* __restrict__ rows,
                        float* __restrict__ dinv) {
    __shared__ int hist[BKT_SZ];
    __shared__ int cur[BKT_SZ];
    int b = blockIdx.x;
    int s0 = bstart[b], e0 = bstart[b + 1];
    if (threadIdx.x < BKT_SZ) hist[threadIdx.x] = 0;
    __syncthreads();
    for (int i = s0 + threadIdx.x; i < e0; i += 256)
        atomicAdd(&hist[ebuf[i] & BKT_MASK], 1);
    __syncthreads();
    if (threadIdx.x < BKT_SZ) {           // wave 0: 64-wide exclusive scan
        int t = threadIdx.x;
        int v = hist[t];
        int p = v;
#pragma unroll
        for (int off = 1; off < 64; off <<= 1) {
            int u = __shfl_up(p, off, 64);
            if (t >= off) p += u;
        }
        int excl = s0 + p - v;
        cur[t] = excl;
        int node = b * BKT_SZ + t;
        if (node <= N_NODES) rows[node] = excl;    // node==N gets N_EDGES naturally
        if (node < N_NODES)  dinv[node] = rsqrtf((float)(v + 1));   // +1 self loop
    }
    __syncthreads();
    for (int i = s0 + threadIdx.x; i < e0; i += 256) {
        unsigned v = ebuf[i];
        int pos = atomicAdd(&cur[v & BKT_MASK], 1);
        csr[pos] = (int)(v >> BKT_SHIFT);
    }
}

// hs[i][c] = dinv[i] * sum_k x[i][k] * W1[k][c]   (x staged via coalesced LDS)
__launch_bounds__(256)
__global__ void k_gemm1(const float* __restrict__ x, const float* __restrict__ W1,
                        const float* __restrict__ dinv, float* __restrict__ hs) {
    __shared__ float w[IN_CH * HID];    // 16 KB
    __shared__ float xs[8 * IN_CH];     // 4 KB
    for (int i = threadIdx.x; i < IN_CH * HID; i += 256) w[i] = W1[i];
    const float4* xb = (const float4*)(x + (size_t)blockIdx.x * 8 * IN_CH);
    ((float4*)xs)[threadIdx.x] = xb[threadIdx.x];   // 256 * 16B = 4KB exact
    __syncthreads();
    int lane = threadIdx.x & 31, hw = threadIdx.x >> 5;
    int node = blockIdx.x * 8 + hw;
    const float* xr = xs + hw * IN_CH;
    float acc = 0.f;
#pragma unroll
    for (int k = 0; k < IN_CH; ++k) acc += xr[k] * w[k * HID + lane];
    hs[(size_t)node * HID + lane] = acc * dinv[node];
}

// conv1 aggregation: one half-wave per node, register accumulate, ILP-8 gathers.
// Fused: h1 = relu(.*dinv + b1); hs2 = (h1 @ W2) * dinv
__launch_bounds__(256)
__global__ void k_agg1(const float* __restrict__ hs, const int* __restrict__ csr,
                       const int* __restrict__ rows, const float* __restrict__ dinv,
                       const float* __restrict__ b1, const float* __restrict__ W2,
                       float* __restrict__ hs2) {
    __shared__ float w2[HID * HID];     // 4 KB
    __shared__ float h1s[8][HID];       // 1 KB
    for (int i = threadIdx.x; i < HID * HID; i += 256) w2[i] = W2[i];
    int lane = threadIdx.x & 31, hw = threadIdx.x >> 5;
    int node = blockIdx.x * 8 + hw;
    int r0 = rows[node], r1 = rows[node + 1];
    float acc = hs[(size_t)node * HID + lane];      // self loop
    int j = r0;
    for (; j + 8 <= r1; j += 8) {
        int t0 = csr[j + 0], t1 = csr[j + 1], t2 = csr[j + 2], t3 = csr[j + 3];
        int t4 = csr[j + 4], t5 = csr[j + 5], t6 = csr[j + 6], t7 = csr[j + 7];
        float f0 = hs[(size_t)t0 * HID + lane];
        float f1 = hs[(size_t)t1 * HID + lane];
        float f2 = hs[(size_t)t2 * HID + lane];
        float f3 = hs[(size_t)t3 * HID + lane];
        float f4 = hs[(size_t)t4 * HID + lane];
        float f5 = hs[(size_t)t5 * HID + lane];
        float f6 = hs[(size_t)t6 * HID + lane];
        float f7 = hs[(size_t)t7 * HID + lane];
        acc += ((f0 + f1) + (f2 + f3)) + ((f4 + f5) + (f6 + f7));
    }
    for (; j < r1; ++j) acc += hs[(size_t)csr[j] * HID + lane];
    float dv = dinv[node];
    h1s[hw][lane] = fmaxf(acc * dv + b1[lane], 0.f);
    __syncthreads();
    float a = 0.f;
#pragma unroll
    for (int k = 0; k < HID; ++k) a += h1s[hw][k] * w2[k * HID + lane];
    hs2[(size_t)node * HID + lane] = a * dv;
}

// conv2 aggregation + relu + fused MLP head
__launch_bounds__(256)
__global__ void k_agg2(const float* __restrict__ hs2, const int* __restrict__ csr,
                       const int* __restrict__ rows, const float* __restrict__ dinv,
                       const float* __restrict__ b2,
                       const float* __restrict__ Wl1, const float* __restrict__ bl1,
                       const float* __restrict__ Wl2, const float* __restrict__ bl2,
                       float* __restrict__ out) {
    __shared__ float wl1[HID * HID];
    __shared__ float h2s[8][HID];
    for (int i = threadIdx.x; i < HID * HID; i += 256) wl1[i] = Wl1[i];
    int lane = threadIdx.x & 31, hw = threadIdx.x >> 5;
    int node = blockIdx.x * 8 + hw;
    int r0 = rows[node], r1 = rows[node + 1];
    float acc = hs2[(size_t)node * HID + lane];
    int j = r0;
    for (; j + 8 <= r1; j += 8) {
        int t0 = csr[j + 0], t1 = csr[j + 1], t2 = csr[j + 2], t3 = csr[j + 3];
        int t4 = csr[j + 4], t5 = csr[j + 5], t6 = csr[j + 6], t7 = csr[j + 7];
        float f0 = hs2[(size_t)t0 * HID + lane];
        float f1 = hs2[(size_t)t1 * HID + lane];
        float f2 = hs2[(size_t)t2 * HID + lane];
        float f3 = hs2[(size_t)t3 * HID + lane];
        float f4 = hs2[(size_t)t4 * HID + lane];
        float f5 = hs2[(size_t)t5 * HID + lane];
        float f6 = hs2[(size_t)t6 * HID + lane];
        float f7 = hs2[(size_t)t7 * HID + lane];
        acc += ((f0 + f1) + (f2 + f3)) + ((f4 + f5) + (f6 + f7));
    }
    for (; j < r1; ++j) acc += hs2[(size_t)csr[j] * HID + lane];
    float h2 = fmaxf(acc * dinv[node] + b2[lane], 0.f);
    h2s[hw][lane] = h2;
    __syncthreads();
    float a = bl1[lane];
#pragma unroll
    for (int k = 0; k < HID; ++k) a += h2s[hw][k] * wl1[k * HID + lane];
    float o = fmaxf(a, 0.f) * Wl2[lane];
#pragma unroll
    for (int off = 16; off; off >>= 1) o += __shfl_down(o, off, 32);
    if (lane == 0) out[node] = o + *bl2;
}

extern "C" void kernel_launch(void* const* d_in, const int* in_sizes, int n_in,
                              void* d_out, int out_size, void* d_ws, size_t ws_size,
                              hipStream_t stream) {
    const float* x   = (const float*)d_in[0];
    const int*   e   = (const int*)d_in[1];
    const float* W1  = (const float*)d_in[2];
    const float* b1  = (const float*)d_in[3];
    const float* W2  = (const float*)d_in[4];
    const float* b2  = (const float*)d_in[5];
    const float* Wl1 = (const float*)d_in[6];
    const float* bl1 = (const float*)d_in[7];
    const float* Wl2 = (const float*)d_in[8];
    const float* bl2 = (const float*)d_in[9];
    float* out = (float*)d_out;

    char* w = (char*)d_ws;
    unsigned int* ebuf    = (unsigned int*)(w + O_EBUF);
    float*        hs      = (float*)(w + O_HS);
    float*        hs2     = (float*)(w + O_HS2);
    int*          ghist   = (int*)(w + O_GH);
    int*          cursors = (int*)(w + O_CUR);
    int*          csr     = (int*)(w + O_CSR);
    int*          rows    = (int*)(w + O_ROWS);
    float*        dinv    = (float*)(w + O_DINV);
    int*          bstart  = (int*)(w + O_BST);
    int*          btot    = (int*)(w + O_BTOT);
    int*          flag    = (int*)(w + O_FLAG);

    const int NB_BIN  = (NBKT + 255) / 256;   // 7
    const int NB_NODE = N_NODES / 8;          // 12500 (exact)

    k_detect<<<1, 256, 0, stream>>>((const unsigned int*)e, flag);
    k_hist<<<NBLK, 256, 0, stream>>>(e, flag, ghist);
    k_scan1<<<NB_BIN, 256, 0, stream>>>(ghist, btot);
    k_scan2<<<1, 1024, 0, stream>>>(btot, bstart);
    k_scan3<<<NB_BIN, 256, 0, stream>>>(ghist, bstart, cursors);
    k_scatter<<<NBLK, 256, 0, stream>>>(e, flag, cursors, ebuf);
    k_sort2<<<NBKT, 256, 0, stream>>>(ebuf, bstart, csr, rows, dinv);

    k_gemm1<<<NB_NODE, 256, 0, stream>>>(x, W1, dinv, hs);
    k_agg1<<<NB_NODE, 256, 0, stream>>>(hs, csr, rows, dinv, b1, W2, hs2);
    k_agg2<<<NB_NODE, 256, 0, stream>>>(hs2, csr, rows, dinv, b2,
                                        Wl1, bl1, Wl2, bl2, out);
}